// Round 5
// baseline (941.792 us; speedup 1.0000x reference)
//
#include <hip/hip_runtime.h>
#include <hip/hip_fp8.h>
#include <cstddef>
#include <cstdint>

typedef _Float16 h4 __attribute__((ext_vector_type(4)));
typedef _Float16 h8 __attribute__((ext_vector_type(8)));
typedef float    f4 __attribute__((ext_vector_type(4)));

#define NN      50000
#define IND     512
#define HIDN    256
#define E2P     400000
#define EDD     800000
#define NBLK    196   // ceil(NN/256)

// ---- workspace layout (bytes) ----
#define OFF_HF16    ((size_t)0)            // 25.6 MB f16 h [NN][256] (dead after k_logits)
#define OFF_LOGF    ((size_t)0)            // 12.8 MB f16 [EDD][8] CSR (aliases hf)
#define OFF_H8Q     ((size_t)25600000)     // 12.8 MB fp8 h [NN][256] (dead after k_edge)
#define OFF_LOGPHI  ((size_t)38400000)     //  1.6 MB f32 [NN][8]
#define OFF_DEG     ((size_t)40000000)     //  int [NN]
#define OFF_LOGDEG  ((size_t)40200000)
#define OFF_DEGC    ((size_t)40400000)
#define OFF_BASE    ((size_t)40600000)
#define OFF_CNT     ((size_t)40800000)
#define OFF_BLK     ((size_t)41000000)     //  4 KB
#define OFF_WT      ((size_t)41004096)     //  256 KB f16 enc_w1^T
#define OFF_BT      ((size_t)41266240)     //  68 KB f16 edge_w1 perm^T
#define OFF_RS      ((size_t)41335872)     //  512 B f32 Rs[64] + alpha at [64]
#define OFF_WSYM    ((size_t)41336384)     //  1.6 MB f32 [E2P]
#define OFF_POS     ((size_t)42936384)     //  3.2 MB int [EDD]
#define OFF_SRC     ((size_t)46136384)     //  3.2 MB int [EDD] CSR
#define OFF_RPOS    ((size_t)49336384)     //  3.2 MB int [EDD] CSR
#define OFF_WN      ((size_t)52536384)     //  6.4 MB float2 [EDD] CSR {w, nrm}
#define OFF_MA      ((size_t)58936384)     // 12.8 MB f16 [EDD][8] CSR
#define OFF_MB      ((size_t)71736384)     // 12.8 MB
#define OFF_SA      ((size_t)84536384)     //  1.6 MB f32 [NN][8] (alpha-scaled)
#define OFF_SB      ((size_t)86136384)     //  1.6 MB
#define WS_NEED     ((size_t)87736384)

__device__ inline unsigned char f32_to_fp8(float v) {
    __hip_fp8_e4m3 t(v);
    return (unsigned char)t.__x;
}
__device__ inline float fp8_to_f32(unsigned char b) {
    __hip_fp8_e4m3 t; t.__x = (__hip_fp8_storage_t)b;
    return (float)t;
}

// ---------------- degree count ----------------
__global__ void k_deg(const int* __restrict__ ei, int* __restrict__ deg) {
    int e = blockIdx.x * 256 + threadIdx.x;   // grid exact: EDD
    atomicAdd(&deg[ei[e]], 1);
}

__global__ void k_node(const int* __restrict__ deg, float* __restrict__ logdeg,
                       float* __restrict__ degc) {
    int n = blockIdx.x * 256 + threadIdx.x;
    if (n < NN) {
        float d = (float)deg[n];
        logdeg[n] = logf(d + 1.0f);
        degc[n]   = fmaxf(d, 1.0f);
    }
}

// ---------------- CSR prefix-sum ----------------
__global__ void k_scan1(const int* __restrict__ deg, int* __restrict__ incl,
                        int* __restrict__ blk) {
    __shared__ int sm[256];
    int i = blockIdx.x * 256 + threadIdx.x;
    int v = (i < NN) ? deg[i] : 0;
    sm[threadIdx.x] = v;
    __syncthreads();
    for (int off = 1; off < 256; off <<= 1) {
        int t = (threadIdx.x >= off) ? sm[threadIdx.x - off] : 0;
        __syncthreads();
        sm[threadIdx.x] += t;
        __syncthreads();
    }
    if (i < NN) incl[i] = sm[threadIdx.x];
    if (threadIdx.x == 255) blk[blockIdx.x] = sm[255];
}

__global__ void k_scan2(int* __restrict__ blk) {
    __shared__ int sm[256];
    int v = (threadIdx.x < NBLK) ? blk[threadIdx.x] : 0;
    sm[threadIdx.x] = v;
    __syncthreads();
    for (int off = 1; off < 256; off <<= 1) {
        int t = (threadIdx.x >= off) ? sm[threadIdx.x - off] : 0;
        __syncthreads();
        sm[threadIdx.x] += t;
        __syncthreads();
    }
    if (threadIdx.x < NBLK) blk[threadIdx.x] = sm[threadIdx.x];
}

__global__ void k_scan3(const int* __restrict__ incl, const int* __restrict__ deg,
                        const int* __restrict__ blk, int* __restrict__ base) {
    int i = blockIdx.x * 256 + threadIdx.x;
    if (i < NN) {
        int off = (blockIdx.x > 0) ? blk[blockIdx.x - 1] : 0;
        base[i] = off + incl[i] - deg[i];
    }
}

__global__ void k_pos(const int* __restrict__ ei, const int* __restrict__ base,
                      int* __restrict__ cnt, int* __restrict__ pos) {
    int e = blockIdx.x * 256 + threadIdx.x;   // grid exact: EDD
    int dstn = ei[EDD + e];
    pos[e] = base[dstn] + atomicAdd(&cnt[dstn], 1);
}

// one-time scatter of per-slot constants into CSR order
__global__ void k_fill(const int* __restrict__ ei, const int* __restrict__ pos,
                       const float* __restrict__ wsym, const float* __restrict__ degc,
                       int* __restrict__ src_csr, int* __restrict__ rpos_csr,
                       float2* __restrict__ wn_csr) {
    int e = blockIdx.x * 256 + threadIdx.x;   // grid exact: EDD
    int s = pos[e];
    int p   = (e < E2P) ? e : e - E2P;
    int rev = (e < E2P) ? e + E2P : e - E2P;
    src_csr[s]  = ei[e];
    rpos_csr[s] = pos[rev];
    int sp = ei[p], dp = ei[EDD + p];
    wn_csr[s] = make_float2(wsym[p], rsqrtf(degc[sp] * degc[dp]));
}

// ---------------- weight prep ----------------
__global__ void k_prep(const float* __restrict__ enc_w1, const float* __restrict__ edge_w1,
                       const float* __restrict__ R_raw, const float* __restrict__ Rsl,
                       const float* __restrict__ mlog,
                       _Float16* __restrict__ Wt, _Float16* __restrict__ Bt,
                       float* __restrict__ Rs) {
    int gid = blockIdx.x * 256 + threadIdx.x;
    if (gid < 256 * 512) {                       // Wt[n][k] = enc_w1[k][n]
        int n = gid >> 9, k = gid & 511;
        Wt[n * 512 + k] = (_Float16)enc_w1[k * 256 + n];
        return;
    }
    int g2 = gid - 256 * 512;
    if (g2 < 64 * 544) {                         // Bt[n][k'] with interleaved K perm
        int n = g2 / 544, k = g2 - n * 544;
        float v = 0.0f;
        if (k < 512) {
            int orig = (k & 1) ? 256 + (k >> 1) : (k >> 1);
            v = edge_w1[orig * 64 + n];
        } else if (k < 514) {
            v = edge_w1[k * 64 + n];
        }
        Bt[n * 544 + k] = (_Float16)v;
        return;
    }
    int g3 = g2 - 64 * 544;
    if (g3 < 64) {
        int c = g3 >> 3, d = g3 & 7;
        float rv = 0.5f * (R_raw[c * 8 + d] + R_raw[d * 8 + c]);
        float s  = log1pf(expf(Rsl[0])) + 1e-6f;
        Rs[g3] = s * tanhf(rv);
        return;
    }
    if (g3 == 64) {
        Rs[64] = 1.5f / (1.0f + expf(-mlog[0]));
    }
}

// ---------------- encoder layer 1 (f16 MFMA) + fp8 shadow copy ----------------
__global__ __launch_bounds__(256) void k_enc(const float* __restrict__ x,
                                             const _Float16* __restrict__ Wt,
                                             const float* __restrict__ b1,
                                             _Float16* __restrict__ hf,
                                             unsigned char* __restrict__ h8q) {
    __shared__ _Float16 XL[64 * 40];
    __shared__ _Float16 WL[256 * 40];
    const int tid = threadIdx.x;
    const int wid = tid >> 6;
    const int lane = tid & 63;
    const int l15 = lane & 15;
    const int q = lane >> 4;
    const int m0 = blockIdx.x * 64;

    f4 acc[16];
#pragma unroll
    for (int i = 0; i < 16; i++) acc[i] = (f4){0.f, 0.f, 0.f, 0.f};

    const int xr = tid >> 2;
    const int xs = tid & 3;
    const int gr = m0 + xr;

    for (int kt = 0; kt < 16; kt++) {
        __syncthreads();
        f4 xv0 = (f4){0, 0, 0, 0}, xv1 = (f4){0, 0, 0, 0};
        if (gr < NN) {
            const f4* xp = (const f4*)(x + (size_t)gr * IND + kt * 32 + xs * 8);
            xv0 = xp[0]; xv1 = xp[1];
        }
        h8 xh;
#pragma unroll
        for (int u = 0; u < 4; u++) { xh[u] = (_Float16)xv0[u]; xh[4 + u] = (_Float16)xv1[u]; }
        *(h8*)&XL[xr * 40 + xs * 8] = xh;
#pragma unroll
        for (int rep = 0; rep < 4; rep++) {
            int cid = rep * 256 + tid;
            int n = cid >> 2;
            int off = (cid & 3) * 8;
            h8 wv = *(const h8*)(Wt + (size_t)n * IND + kt * 32 + off);
            *(h8*)&WL[n * 40 + off] = wv;
        }
        __syncthreads();
        h8 a = *(const h8*)&XL[(wid * 16 + l15) * 40 + q * 8];
#pragma unroll
        for (int nt = 0; nt < 16; nt++) {
            h8 b = *(const h8*)&WL[(nt * 16 + l15) * 40 + q * 8];
            acc[nt] = __builtin_amdgcn_mfma_f32_16x16x32_f16(a, b, acc[nt], 0, 0, 0);
        }
    }
#pragma unroll
    for (int nt = 0; nt < 16; nt++) {
        int col = nt * 16 + l15;
        float bv = b1[col];
#pragma unroll
        for (int reg = 0; reg < 4; reg++) {
            int row = m0 + wid * 16 + q * 4 + reg;
            if (row < NN) {
                float v = fmaxf(acc[nt][reg] + bv, 0.f);
                hf[(size_t)row * HIDN + col] = (_Float16)v;
                h8q[(size_t)row * HIDN + col] = f32_to_fp8(v);
            }
        }
    }
}

// ---------------- encoder layer 2 + log_softmax ----------------
__global__ void k_logits(const _Float16* __restrict__ hf, const float* __restrict__ w2,
                         const float* __restrict__ b2, float* __restrict__ log_phi) {
    __shared__ float w2L[2048];
    for (int i = threadIdx.x; i < 2048; i += 256) w2L[i] = w2[i];
    __syncthreads();
    int n = blockIdx.x * 256 + threadIdx.x;
    if (n >= NN) return;
    float sum[8];
#pragma unroll
    for (int c = 0; c < 8; c++) sum[c] = b2[c];
    for (int kb = 0; kb < 32; kb++) {
        h8 hv = *(const h8*)(hf + (size_t)n * HIDN + kb * 8);
#pragma unroll
        for (int u = 0; u < 8; u++) {
            float hx = (float)hv[u];
            const float* wr = &w2L[(kb * 8 + u) * 8];
#pragma unroll
            for (int c = 0; c < 8; c++) sum[c] += hx * wr[c];
        }
    }
    float mx = sum[0];
#pragma unroll
    for (int c = 1; c < 8; c++) mx = fmaxf(mx, sum[c]);
    float se = 0.f;
#pragma unroll
    for (int c = 0; c < 8; c++) se += __expf(sum[c] - mx);
    float lse = __logf(se);
#pragma unroll
    for (int c = 0; c < 8; c++) log_phi[(size_t)n * 8 + c] = sum[c] - mx - lse;
}

// ---------------- edge MLP (pairs only), fp8 gathers ----------------
__global__ __launch_bounds__(256) void k_edge(const int* __restrict__ ei,
        const unsigned char* __restrict__ h8q, const float* __restrict__ logdeg,
        const _Float16* __restrict__ BtG, const float* __restrict__ eb1,
        const float* __restrict__ ew2, const float* __restrict__ eb2,
        float* __restrict__ wsym) {
    __shared__ _Float16 BtL[64 * 168];
    const int tid = threadIdx.x;
    const int wid = tid >> 6;
    const int lane = tid & 63;
    const int l15 = lane & 15;
    const int q = lane >> 4;
    const int eb = blockIdx.x * 256;

    int sidx[4], didx[4];
    float la[4], lb[4];
#pragma unroll
    for (int mt = 0; mt < 4; mt++) {
        int e = eb + wid * 64 + mt * 16 + l15;
        int ee = (e < E2P) ? e : 0;
        sidx[mt] = ei[ee];
        didx[mt] = ei[EDD + ee];
        la[mt] = logdeg[sidx[mt]];
        lb[mt] = logdeg[didx[mt]];
    }

    f4 acc[4][4];
#pragma unroll
    for (int a = 0; a < 4; a++)
#pragma unroll
        for (int b = 0; b < 4; b++) acc[a][b] = (f4){0.f, 0.f, 0.f, 0.f};

    const unsigned char* hq = h8q + q * 4;
    unsigned curS[4], curD[4];
#pragma unroll
    for (int mt = 0; mt < 4; mt++) {            // kt=0 fragments (4 fp8 = 4 B)
        curS[mt] = *(const unsigned*)(hq + (size_t)sidx[mt] * HIDN);
        curD[mt] = *(const unsigned*)(hq + (size_t)didx[mt] * HIDN);
    }

    for (int ph = 0; ph < 4; ph++) {
        const int kbase = ph * 160;
        const int nch = (ph == 3) ? 8 : 20;
        __syncthreads();
        {
            const int r = tid & 63;
            const int cb = tid >> 6;
            for (int ck = cb; ck < nch; ck += 4) {
                h8 v = *(const h8*)(BtG + (size_t)r * 544 + kbase + ck * 8);
                *(h8*)&BtL[r * 168 + ck * 8] = v;
            }
        }
        __syncthreads();
        const int kt0 = ph * 5;
        const int kt1 = (ph == 3) ? 17 : kt0 + 5;
        for (int kt = kt0; kt < kt1; kt++) {
            unsigned nxtS[4], nxtD[4];
            if (kt < 15) {                      // prefetch kt+1 gathers
                const int c1 = (kt + 1) * 16;
#pragma unroll
                for (int mt = 0; mt < 4; mt++) {
                    nxtS[mt] = *(const unsigned*)(hq + (size_t)sidx[mt] * HIDN + c1);
                    nxtD[mt] = *(const unsigned*)(hq + (size_t)didx[mt] * HIDN + c1);
                }
            }
            h8 af[4];
            if (kt < 16) {
#pragma unroll
                for (int mt = 0; mt < 4; mt++) {
                    h8 a;
#pragma unroll
                    for (int u = 0; u < 4; u++) {
                        float x1 = fp8_to_f32((curS[mt] >> (8 * u)) & 0xff);
                        float x2 = fp8_to_f32((curD[mt] >> (8 * u)) & 0xff);
                        a[2 * u]     = (_Float16)(x1 * x2);
                        a[2 * u + 1] = (_Float16)fabsf(x1 - x2);
                    }
                    af[mt] = a;
                }
            } else {
#pragma unroll
                for (int mt = 0; mt < 4; mt++) {
                    h8 a = (h8){0, 0, 0, 0, 0, 0, 0, 0};
                    if (q == 0) {
                        a[0] = (_Float16)(la[mt] + lb[mt]);
                        a[1] = (_Float16)fabsf(la[mt] - lb[mt]);
                    }
                    af[mt] = a;
                }
            }
            const int ko = kt * 32 - kbase + q * 8;
            h8 bf[4];
#pragma unroll
            for (int nt = 0; nt < 4; nt++)
                bf[nt] = *(const h8*)&BtL[(nt * 16 + l15) * 168 + ko];
#pragma unroll
            for (int mt = 0; mt < 4; mt++)
#pragma unroll
                for (int nt = 0; nt < 4; nt++)
                    acc[mt][nt] = __builtin_amdgcn_mfma_f32_16x16x32_f16(af[mt], bf[nt], acc[mt][nt], 0, 0, 0);
            if (kt < 15) {
#pragma unroll
                for (int mt = 0; mt < 4; mt++) { curS[mt] = nxtS[mt]; curD[mt] = nxtD[mt]; }
            }
        }
    }

    float b1v[4], w2v[4];
#pragma unroll
    for (int nt = 0; nt < 4; nt++) {
        int col = nt * 16 + l15;
        b1v[nt] = eb1[col];
        w2v[nt] = ew2[col];
    }
    const float b2s = eb2[0];
    float part[4][4];
#pragma unroll
    for (int mt = 0; mt < 4; mt++)
#pragma unroll
        for (int reg = 0; reg < 4; reg++) {
            float s = 0.f;
#pragma unroll
            for (int nt = 0; nt < 4; nt++) {
                float v = acc[mt][nt][reg] + b1v[nt];
                s += fmaxf(v, 0.f) * w2v[nt];
            }
            part[mt][reg] = s;
        }
#pragma unroll
    for (int off = 1; off < 16; off <<= 1)
#pragma unroll
        for (int mt = 0; mt < 4; mt++)
#pragma unroll
            for (int reg = 0; reg < 4; reg++)
                part[mt][reg] += __shfl_xor(part[mt][reg], off, 64);
    if (l15 == 0) {
#pragma unroll
        for (int mt = 0; mt < 4; mt++)
#pragma unroll
            for (int reg = 0; reg < 4; reg++) {
                int er = eb + wid * 64 + mt * 16 + q * 4 + reg;
                if (er < E2P) {
                    float xr = part[mt][reg] + b2s;
                    wsym[er] = 0.8f / (1.0f + __expf(-xr));
                }
            }
    }
}

// ======== BP: CSR-slot-centric, contiguous writes only ========

// init: m = softmax(log_phi[src]) per slot; logf from m
__global__ __launch_bounds__(256) void k_initC(const int* __restrict__ src_csr,
        const float2* __restrict__ wn_csr, const float* __restrict__ Rs,
        const float* __restrict__ log_phi, _Float16* __restrict__ m_csr,
        _Float16* __restrict__ logfb) {
    __shared__ float RsL[64];
    const int tid = threadIdx.x;
    if (tid < 64) RsL[tid] = Rs[tid];
    __syncthreads();
    int s = blockIdx.x * 256 + tid;   // grid exact: EDD
    int src = src_csr[s];
    float2 wn = wn_csr[s];
    const f4* lpp = (const f4*)(log_phi + (size_t)src * 8);
    f4 l0 = lpp[0], l1 = lpp[1];
    float lp[8];
#pragma unroll
    for (int u = 0; u < 4; u++) { lp[u] = l0[u]; lp[4 + u] = l1[u]; }
    float m[8];
    float mx = lp[0];
#pragma unroll
    for (int d = 1; d < 8; d++) mx = fmaxf(mx, lp[d]);
    float sum = 0.f;
#pragma unroll
    for (int d = 0; d < 8; d++) { m[d] = __expf(lp[d] - mx); sum += m[d]; }
    float rs = 1.f / sum;
#pragma unroll
    for (int d = 0; d < 8; d++) m[d] *= rs;
    h8 mh;
#pragma unroll
    for (int d = 0; d < 8; d++) mh[d] = (_Float16)m[d];
    *(h8*)(m_csr + (size_t)s * 8) = mh;
    float f[8];
#pragma unroll
    for (int d = 0; d < 8; d++) f[d] = 0.f;
#pragma unroll
    for (int c = 0; c < 8; c++) {
#pragma unroll
        for (int d = 0; d < 8; d++)
            f[d] += m[c] * __expf(wn.x * RsL[c * 8 + d]);
    }
    h8 lf;
#pragma unroll
    for (int d = 0; d < 8; d++)
        lf[d] = (_Float16)(__logf(fmaxf(f[d], 1e-12f)) * wn.y);
    *(h8*)(logfb + (size_t)s * 8) = lf;
}

// sum_in (alpha-scaled): contiguous CSR segment reduction
__global__ void k_sum(const _Float16* __restrict__ logfb, const int* __restrict__ base,
                      const int* __restrict__ deg, const float* __restrict__ Rs,
                      float* __restrict__ S) {
    int tid = blockIdx.x * 256 + threadIdx.x;
    if (tid >= NN * 8) return;
    int n = tid >> 3, d = tid & 7;
    int b = base[n], cnt = deg[n];
    float s = 0.f;
    for (int j = 0; j < cnt; j++)
        s += (float)logfb[(size_t)(b + j) * 8 + d];
    S[tid] = Rs[64] * s;
}

// BP step per slot: contiguous reads/writes; gathers: m_rev, log_phi[src], S[src]
__global__ __launch_bounds__(256) void k_bpC(const int* __restrict__ src_csr,
        const int* __restrict__ rpos_csr, const float2* __restrict__ wn_csr,
        const float* __restrict__ Rs, const float* __restrict__ log_phi,
        const _Float16* __restrict__ m_csr, const float* __restrict__ Sa,
        _Float16* __restrict__ mo_csr, _Float16* __restrict__ logfb) {
    __shared__ float RsL[64];
    const int tid = threadIdx.x;
    if (tid < 64) RsL[tid] = Rs[tid];
    __syncthreads();
    int s = blockIdx.x * 256 + tid;   // grid exact: EDD
    int src = src_csr[s];
    int rp  = rpos_csr[s];
    float2 wn = wn_csr[s];
    const float alpha = Rs[64];
    h8 mhs = *(const h8*)(m_csr + (size_t)s * 8);
    h8 mhr = *(const h8*)(m_csr + (size_t)rp * 8);      // random 16B gather
    float me[8], mr[8];
#pragma unroll
    for (int d = 0; d < 8; d++) { me[d] = (float)mhs[d]; mr[d] = (float)mhr[d]; }
    // K in registers (shared by rev direction: same w)
    float K[8][8];
#pragma unroll
    for (int c = 0; c < 8; c++)
#pragma unroll
        for (int d = 0; d < 8; d++)
            K[c][d] = __expf(wn.x * RsL[c * 8 + d]);
    // f_rev -> log_f[rev]
    float fr[8];
#pragma unroll
    for (int d = 0; d < 8; d++) fr[d] = 0.f;
#pragma unroll
    for (int c = 0; c < 8; c++)
#pragma unroll
        for (int d = 0; d < 8; d++) fr[d] += mr[c] * K[c][d];
    const f4* lpp = (const f4*)(log_phi + (size_t)src * 8);
    const f4* Sp  = (const f4*)(Sa + (size_t)src * 8);
    f4 l0 = lpp[0], l1 = lpp[1], s0 = Sp[0], s1 = Sp[1];
    float anrm = alpha * wn.y;
    float te[8];
#pragma unroll
    for (int u = 0; u < 4; u++) {
        te[u]     = l0[u] + s0[u] - anrm * __logf(fmaxf(fr[u], 1e-12f));
        te[4 + u] = l1[u] + s1[u] - anrm * __logf(fmaxf(fr[4 + u], 1e-12f));
    }
    // softmax + damping + renorm
    float m1[8];
    float mx = te[0];
#pragma unroll
    for (int d = 1; d < 8; d++) mx = fmaxf(mx, te[d]);
    float sum = 0.f;
#pragma unroll
    for (int d = 0; d < 8; d++) { m1[d] = __expf(te[d] - mx); sum += m1[d]; }
    float rs = 1.f / sum;
    float t1 = 0.f;
#pragma unroll
    for (int d = 0; d < 8; d++) {
        m1[d] = fmaxf(0.8f * me[d] + 0.2f * m1[d] * rs, 1e-12f);
        t1 += m1[d];
    }
    float rt = 1.f / t1;
#pragma unroll
    for (int d = 0; d < 8; d++) m1[d] *= rt;
    h8 mh;
#pragma unroll
    for (int d = 0; d < 8; d++) mh[d] = (_Float16)m1[d];
    *(h8*)(mo_csr + (size_t)s * 8) = mh;
    // new log_f from m_new (K reused)
    float fn[8];
#pragma unroll
    for (int d = 0; d < 8; d++) fn[d] = 0.f;
#pragma unroll
    for (int c = 0; c < 8; c++)
#pragma unroll
        for (int d = 0; d < 8; d++) fn[d] += m1[c] * K[c][d];
    h8 lf;
#pragma unroll
    for (int d = 0; d < 8; d++)
        lf[d] = (_Float16)(__logf(fmaxf(fn[d], 1e-12f)) * wn.y);
    *(h8*)(logfb + (size_t)s * 8) = lf;
}

// ---------------- beliefs = softmax(log_phi + Sa) ----------------
__global__ void k_bel(const float* __restrict__ log_phi, const float* __restrict__ Sa,
                      float* __restrict__ out) {
    int tid = blockIdx.x * 256 + threadIdx.x;
    if (tid >= NN * 8) return;
    float v = log_phi[tid] + Sa[tid];
    float mx = v;
    mx = fmaxf(mx, __shfl_xor(mx, 1, 64));
    mx = fmaxf(mx, __shfl_xor(mx, 2, 64));
    mx = fmaxf(mx, __shfl_xor(mx, 4, 64));
    float ex = __expf(v - mx);
    float s = ex;
    s += __shfl_xor(s, 1, 64); s += __shfl_xor(s, 2, 64); s += __shfl_xor(s, 4, 64);
    out[tid] = ex / s;
}

extern "C" void kernel_launch(void* const* d_in, const int* in_sizes, int n_in,
                              void* d_out, int out_size, void* d_ws, size_t ws_size,
                              hipStream_t stream) {
    if (ws_size < WS_NEED) return;
    const float* x        = (const float*)d_in[0];
    const int*   ei       = (const int*)d_in[1];
    const float* enc_w1   = (const float*)d_in[3];
    const float* enc_b1   = (const float*)d_in[4];
    const float* enc_w2   = (const float*)d_in[5];
    const float* enc_b2   = (const float*)d_in[6];
    const float* edge_w1  = (const float*)d_in[7];
    const float* edge_b1  = (const float*)d_in[8];
    const float* edge_w2  = (const float*)d_in[9];
    const float* edge_b2  = (const float*)d_in[10];
    const float* R_raw    = (const float*)d_in[11];
    const float* Rsl      = (const float*)d_in[12];
    const float* mlog     = (const float*)d_in[13];

    char* ws = (char*)d_ws;
    _Float16* hf     = (_Float16*)(ws + OFF_HF16);
    _Float16* logfb  = (_Float16*)(ws + OFF_LOGF);
    unsigned char* h8q = (unsigned char*)(ws + OFF_H8Q);
    float* log_phi   = (float*)(ws + OFF_LOGPHI);
    int*   deg       = (int*)  (ws + OFF_DEG);
    float* logdeg    = (float*)(ws + OFF_LOGDEG);
    float* degc      = (float*)(ws + OFF_DEGC);
    int*   baseA     = (int*)  (ws + OFF_BASE);
    int*   cnt       = (int*)  (ws + OFF_CNT);
    int*   blk       = (int*)  (ws + OFF_BLK);
    _Float16* Wt     = (_Float16*)(ws + OFF_WT);
    _Float16* Bt     = (_Float16*)(ws + OFF_BT);
    float* Rs        = (float*)(ws + OFF_RS);
    float* wsym      = (float*)(ws + OFF_WSYM);
    int*   pos       = (int*)  (ws + OFF_POS);
    int*   src_csr   = (int*)  (ws + OFF_SRC);
    int*   rpos_csr  = (int*)  (ws + OFF_RPOS);
    float2* wn_csr   = (float2*)(ws + OFF_WN);
    _Float16* mA     = (_Float16*)(ws + OFF_MA);
    _Float16* mB     = (_Float16*)(ws + OFF_MB);
    float* SA        = (float*)(ws + OFF_SA);
    float* SB        = (float*)(ws + OFF_SB);

    hipMemsetAsync(deg, 0, (size_t)NN * 4, stream);
    k_deg<<<dim3(EDD / 256), dim3(256), 0, stream>>>(ei, deg);
    k_node<<<dim3(NBLK), dim3(256), 0, stream>>>(deg, logdeg, degc);
    k_prep<<<dim3((256 * 512 + 64 * 544 + 65 + 255) / 256), dim3(256), 0, stream>>>(
        enc_w1, edge_w1, R_raw, Rsl, mlog, Wt, Bt, Rs);
    // CSR build (one-time)
    k_scan1<<<dim3(NBLK), dim3(256), 0, stream>>>(deg, cnt /*incl scratch*/, blk);
    k_scan2<<<dim3(1), dim3(256), 0, stream>>>(blk);
    k_scan3<<<dim3(NBLK), dim3(256), 0, stream>>>(cnt, deg, blk, baseA);
    hipMemsetAsync(cnt, 0, (size_t)NN * 4, stream);
    k_pos<<<dim3(EDD / 256), dim3(256), 0, stream>>>(ei, baseA, cnt, pos);
    // encoder + edge MLP
    k_enc<<<dim3((NN + 63) / 64), dim3(256), 0, stream>>>(x, Wt, enc_b1, hf, h8q);
    k_logits<<<dim3(NBLK), dim3(256), 0, stream>>>(hf, enc_w2, enc_b2, log_phi);
    k_edge<<<dim3((E2P + 255) / 256), dim3(256), 0, stream>>>(ei, h8q, logdeg, Bt, edge_b1,
                                                              edge_w2, edge_b2, wsym);
    k_fill<<<dim3(EDD / 256), dim3(256), 0, stream>>>(ei, pos, wsym, degc,
                                                      src_csr, rpos_csr, wn_csr);
    // BP loop (logfb aliases hf — hf dead after k_logits)
    k_initC<<<dim3(EDD / 256), dim3(256), 0, stream>>>(src_csr, wn_csr, Rs, log_phi,
                                                       mA, logfb);
    k_sum<<<dim3((NN * 8 + 255) / 256), dim3(256), 0, stream>>>(logfb, baseA, deg, Rs, SA);
    _Float16* mc = mA; _Float16* mn = mB;
    float* Sc = SA; float* Sx = SB;
    for (int t = 0; t < 10; t++) {
        k_bpC<<<dim3(EDD / 256), dim3(256), 0, stream>>>(src_csr, rpos_csr, wn_csr, Rs,
                                                         log_phi, mc, Sc, mn, logfb);
        k_sum<<<dim3((NN * 8 + 255) / 256), dim3(256), 0, stream>>>(logfb, baseA, deg, Rs, Sx);
        _Float16* tm = mc; mc = mn; mn = tm;
        float* ts = Sc; Sc = Sx; Sx = ts;
    }
    k_bel<<<dim3((NN * 8 + 255) / 256), dim3(256), 0, stream>>>(log_phi, Sc, (float*)d_out);
    (void)in_sizes; (void)n_in; (void)out_size;
}